// Round 3
// baseline (96.964 us; speedup 1.0000x reference)
//
#include <hip/hip_runtime.h>

// GCN 2-layer inference with F_OUT = 1.
//
// The reference ends with jax.nn.log_softmax(h, axis=1) on h of shape
// [N_NODES, 1]. log_softmax over a singleton axis is identically 0.0
// (x - logsumexp(x) over one element = x - x), and every upstream value is
// finite (self-loops ensure deg >= 1; all inputs are finite), so no NaN can
// propagate. The whole GCN is algebraically dead: the output is exactly
// 100000 zeros. Verified on-device (round 2): passed, absmax = 0.0.
//
// Round-2 counters showed our fill kernel's device time is negligible
// (doesn't appear in top-5; 400 KB at ~6.5 TB/s = 0.06 us) — the 96.9 us
// dur_us is fixed per-replay overhead. This round: replace the kernel node
// with a hipMemsetAsync node (graph-capture-legal, cheapest possible node)
// as the final A/B. IEEE-754 float 0.0f is all-zero bits, so memset(0) is
// bit-exact.

extern "C" void kernel_launch(void* const* d_in, const int* in_sizes, int n_in,
                              void* d_out, int out_size, void* d_ws, size_t ws_size,
                              hipStream_t stream) {
    (void)d_in; (void)in_sizes; (void)n_in; (void)d_ws; (void)ws_size;
    // 100000 floats * 4 B = 400 KB of zero bits == 100000 x 0.0f
    hipMemsetAsync(d_out, 0, (size_t)out_size * sizeof(float), stream);
}